// Round 1
// baseline (1434.972 us; speedup 1.0000x reference)
//
#include <hip/hip_runtime.h>
#include <hip/hip_bf16.h>

#define HID 50
#define FOURH 200
#define TSTEPS 2048
#define NBATCH 1024

__device__ __forceinline__ float fast_sigmoid(float x) {
    // 1/(1+e^-x); __expf(inf) -> inf -> 1/inf = 0; safe at both tails
    return 1.0f / (1.0f + __expf(-x));
}

__device__ __forceinline__ float fast_tanh(float x) {
    // tanh(x) = 1 - 2/(e^{2x}+1); saturates to +/-1 without NaN for large |x|
    return 1.0f - 2.0f / (__expf(2.0f * x) + 1.0f);
}

__global__ __launch_bounds__(256, 4)
void lstm_fp32_kernel(const float* __restrict__ x,
                      const float* __restrict__ Wx,
                      const float* __restrict__ Wh,
                      const float* __restrict__ bias,
                      const float* __restrict__ Wd,
                      const float* __restrict__ bd,
                      float* __restrict__ out) {
    const int b   = blockIdx.x;
    const int tid = threadIdx.x;

    __shared__ __align__(16) float hbuf[52];     // h state, padded to 13 float4
    __shared__ __align__(16) float zbuf[FOURH];  // gate pre-activations
    __shared__ __align__(16) float xs[TSTEPS];   // whole input sequence, 8 KB

    // Stage the batch's input sequence into LDS (coalesced).
    const float* xb = x + (size_t)b * TSTEPS;
    #pragma unroll
    for (int t = tid; t < TSTEPS; t += 256) xs[t] = xb[t];

    // Per-thread column weights: Wh[:, j] for j = tid (coalesced across threads).
    float w[52];
    float wx_j = 0.0f, b_j = 0.0f;
    if (tid < FOURH) {
        #pragma unroll
        for (int k = 0; k < HID; ++k) w[k] = Wh[k * FOURH + tid];
        w[50] = 0.0f; w[51] = 0.0f;
        wx_j = Wx[tid];
        b_j  = bias[tid];
    } else {
        #pragma unroll
        for (int k = 0; k < 52; ++k) w[k] = 0.0f;
    }

    if (tid < 52) hbuf[tid] = 0.0f;
    float c = 0.0f;  // cell state for hidden unit tid (tid < 50)
    __syncthreads();

    for (int t = 0; t < TSTEPS; ++t) {
        const float xt = xs[t];
        if (tid < FOURH) {
            float z = fmaf(xt, wx_j, b_j);
            const float4* h4 = (const float4*)hbuf;
            #pragma unroll
            for (int k4 = 0; k4 < 13; ++k4) {
                float4 hv = h4[k4];
                z = fmaf(hv.x, w[4 * k4 + 0], z);
                z = fmaf(hv.y, w[4 * k4 + 1], z);
                z = fmaf(hv.z, w[4 * k4 + 2], z);
                z = fmaf(hv.w, w[4 * k4 + 3], z);
            }
            zbuf[tid] = z;
        }
        __syncthreads();
        if (tid < HID) {
            const float zi = zbuf[tid];
            const float zf = zbuf[tid + HID];
            const float zg = zbuf[tid + 2 * HID];
            const float zo = zbuf[tid + 3 * HID];
            const float ig = fast_sigmoid(zi);
            const float fg = fast_sigmoid(zf);
            const float gg = fast_tanh(zg);
            const float og = fast_sigmoid(zo);
            c = fmaf(fg, c, ig * gg);
            hbuf[tid] = og * fast_tanh(c);
        }
        __syncthreads();
    }

    // out[b] = h_last . Wd + bd  (wave 0 reduction)
    if (tid < 64) {
        float v = (tid < HID) ? hbuf[tid] * Wd[tid] : 0.0f;
        #pragma unroll
        for (int off = 32; off > 0; off >>= 1) v += __shfl_down(v, off);
        if (tid == 0) out[b] = v + bd[0];
    }
}

extern "C" void kernel_launch(void* const* d_in, const int* in_sizes, int n_in,
                              void* d_out, int out_size, void* d_ws, size_t ws_size,
                              hipStream_t stream) {
    const float* x    = (const float*)d_in[0];  // [1024, 2048, 1]
    const float* Wx   = (const float*)d_in[1];  // [1, 200]
    const float* Wh   = (const float*)d_in[2];  // [50, 200]
    const float* bias = (const float*)d_in[3];  // [200]
    const float* Wd   = (const float*)d_in[4];  // [50, 1]
    const float* bd   = (const float*)d_in[5];  // [1]
    float* out = (float*)d_out;                 // [1024, 1]

    lstm_fp32_kernel<<<dim3(NBATCH), dim3(256), 0, stream>>>(
        x, Wx, Wh, bias, Wd, bd, out);
}

// Round 2
// 1061.816 us; speedup vs baseline: 1.3514x; 1.3514x over previous
//
#include <hip/hip_runtime.h>
#include <hip/hip_bf16.h>

#define HID 50
#define FOURH 200
#define TSTEPS 2048
#define NBATCH 1024

typedef float v2f __attribute__((ext_vector_type(2)));

__device__ __forceinline__ float fast_sigmoid(float x) {
    // 1/(1+e^-x); safe at both tails (exp(inf)->inf -> 0)
    return 1.0f / (1.0f + __expf(-x));
}

__device__ __forceinline__ float fast_tanh(float x) {
    // tanh(x) = 1 - 2/(e^{2x}+1); saturates to +/-1 without NaN for large |x|
    return 1.0f - 2.0f / (__expf(2.0f * x) + 1.0f);
}

// One wave (64 threads) per batch element. Lane l owns hidden unit min(l,49):
// it holds Wh columns for all 4 gates of that unit in registers (200 fp32 as
// 100 float2 pairs along k -> v_pk_fma_f32), computes the 4 gate dots, the
// nonlinearities, and the c/h update entirely in-lane. Cross-lane h broadcast
// goes through a 64-entry LDS buffer (broadcast ds_read_b64, conflict-free).
// Lanes 50..63 duplicate unit 49 (finite garbage) and write to private slots.
__global__ __launch_bounds__(64, 1)
void lstm_wave_kernel(const float* __restrict__ x,
                      const float* __restrict__ Wx,
                      const float* __restrict__ Wh,
                      const float* __restrict__ bias,
                      const float* __restrict__ Wd,
                      const float* __restrict__ bd,
                      float* __restrict__ out) {
    const int b    = blockIdx.x;
    const int lane = threadIdx.x;
    const int lc   = (lane < HID) ? lane : (HID - 1);  // clamped unit index

    __shared__ __align__(16) float hbuf[64];       // h state (slots 50..63 scratch)
    __shared__ __align__(16) float xs[TSTEPS];     // whole input sequence, 8 KB

    // Stage input sequence (coalesced float4 loads).
    const float4* xb4 = (const float4*)(x + (size_t)b * TSTEPS);
    float4* xs4 = (float4*)xs;
    #pragma unroll
    for (int i = lane; i < TSTEPS / 4; i += 64) xs4[i] = xb4[i];

    // Load per-unit weights: pair along k so the dot issues as v_pk_fma_f32.
    // w_g[k2] = { Wh[2k2][gcol], Wh[2k2+1][gcol] }, gcol = g*50 + lc.
    v2f w_i[25], w_f[25], w_g[25], w_o[25];
    #pragma unroll
    for (int k2 = 0; k2 < 25; ++k2) {
        const float* r0 = Wh + (2 * k2) * FOURH;
        const float* r1 = Wh + (2 * k2 + 1) * FOURH;
        w_i[k2] = v2f{r0[lc],           r1[lc]};
        w_f[k2] = v2f{r0[HID + lc],     r1[HID + lc]};
        w_g[k2] = v2f{r0[2 * HID + lc], r1[2 * HID + lc]};
        w_o[k2] = v2f{r0[3 * HID + lc], r1[3 * HID + lc]};
    }
    const float wx_i = Wx[lc],           b_i = bias[lc];
    const float wx_f = Wx[HID + lc],     b_f = bias[HID + lc];
    const float wx_g = Wx[2 * HID + lc], b_g = bias[2 * HID + lc];
    const float wx_o = Wx[3 * HID + lc], b_o = bias[3 * HID + lc];

    hbuf[lane] = 0.0f;
    float c = 0.0f;
    float h = 0.0f;
    __syncthreads();

    const v2f* h2p = (const v2f*)hbuf;

    for (int t = 0; t < TSTEPS; ++t) {
        const float xt = xs[t];
        v2f ai = {0.0f, 0.0f}, af = {0.0f, 0.0f};
        v2f ag = {0.0f, 0.0f}, ao = {0.0f, 0.0f};
        #pragma unroll
        for (int k2 = 0; k2 < 25; ++k2) {
            const v2f h2 = h2p[k2];                 // broadcast ds_read_b64
            ai = __builtin_elementwise_fma(w_i[k2], h2, ai);
            af = __builtin_elementwise_fma(w_f[k2], h2, af);
            ag = __builtin_elementwise_fma(w_g[k2], h2, ag);
            ao = __builtin_elementwise_fma(w_o[k2], h2, ao);
        }
        const float zi = fmaf(xt, wx_i, b_i) + ai.x + ai.y;
        const float zf = fmaf(xt, wx_f, b_f) + af.x + af.y;
        const float zg = fmaf(xt, wx_g, b_g) + ag.x + ag.y;
        const float zo = fmaf(xt, wx_o, b_o) + ao.x + ao.y;

        const float ig = fast_sigmoid(zi);
        const float fg = fast_sigmoid(zf);
        const float gg = fast_tanh(zg);
        const float og = fast_sigmoid(zo);
        c = fmaf(fg, c, ig * gg);
        h = og * fast_tanh(c);

        hbuf[lane] = h;        // lanes >=50 write scratch slots (never read)
        __syncthreads();       // single-wave barrier: cheap, orders LDS
    }

    // out[b] = h . Wd + bd
    float v = (lane < HID) ? h * Wd[lane] : 0.0f;
    #pragma unroll
    for (int off = 32; off > 0; off >>= 1) v += __shfl_down(v, off);
    if (lane == 0) out[b] = v + bd[0];
}

extern "C" void kernel_launch(void* const* d_in, const int* in_sizes, int n_in,
                              void* d_out, int out_size, void* d_ws, size_t ws_size,
                              hipStream_t stream) {
    const float* x    = (const float*)d_in[0];  // [1024, 2048, 1]
    const float* Wx   = (const float*)d_in[1];  // [1, 200]
    const float* Wh   = (const float*)d_in[2];  // [50, 200]
    const float* bias = (const float*)d_in[3];  // [200]
    const float* Wd   = (const float*)d_in[4];  // [50, 1]
    const float* bd   = (const float*)d_in[5];  // [1]
    float* out = (float*)d_out;                 // [1024, 1]

    lstm_wave_kernel<<<dim3(NBATCH), dim3(64), 0, stream>>>(
        x, Wx, Wh, bias, Wd, bd, out);
}